// Round 2
// baseline (1699.490 us; speedup 1.0000x reference)
//
#include <hip/hip_runtime.h>
#include <hip/hip_bf16.h>
#include <stdint.h>

typedef __attribute__((ext_vector_type(8))) short bf16x8;
typedef __attribute__((ext_vector_type(4))) float f32x4;

#define DEV static __device__ __forceinline__

DEV void gload_lds16(const __hip_bfloat16* g, __hip_bfloat16* l) {
  __builtin_amdgcn_global_load_lds(
      (const __attribute__((address_space(1))) void*)g,
      (__attribute__((address_space(3))) void*)l, 16, 0, 0);
}

DEV float cvtf(float v) { return v; }
DEV float cvtf(__hip_bfloat16 v) { return __bfloat162float(v); }

// ---------------- transpose(+straight) cast to bf16 ----------------
// src (R,C) -> dst (C,R) [bf16]; optional straight copy dstS (R,C) [bf16]
template<typename TIN, bool STRAIGHT>
__global__ __launch_bounds__(256)
void transpose_cast(const TIN* __restrict__ src, __hip_bfloat16* __restrict__ dst,
                    __hip_bfloat16* __restrict__ dstS, int R, int C,
                    long sSz, long sDz)
{
  __shared__ __hip_bfloat16 tile[64][65];
  const long r0 = (long)blockIdx.x * 64, c0 = (long)blockIdx.y * 64;
  const TIN* s = src + (long)blockIdx.z * sSz;
  __hip_bfloat16* d = dst + (long)blockIdx.z * sDz;
  const int t = threadIdx.x;
#pragma unroll
  for (int e = 0; e < 16; ++e) {
    const int idx = e * 256 + t;
    const int sr = idx >> 6, sc = idx & 63;
    const __hip_bfloat16 b = __float2bfloat16(cvtf(s[(r0 + sr) * C + c0 + sc]));
    tile[sr][sc] = b;
    if (STRAIGHT) dstS[(r0 + sr) * C + c0 + sc] = b;
  }
  __syncthreads();
#pragma unroll
  for (int e = 0; e < 16; ++e) {
    const int idx = e * 256 + t;
    const int dr = idx >> 6, dc = idx & 63;
    d[(c0 + dr) * R + r0 + dc] = tile[dc][dr];
  }
}

// ---------------- dual softmax: D over p (lanes), C over n (per-lane) ----------------
// logits row layout: np = n*64 + p. Wave lane l, reg j holds np = j*64 + l -> n=j, p=l.
__global__ __launch_bounds__(256)
void softmax_kernel(const float* __restrict__ L, __hip_bfloat16* __restrict__ Db,
                    __hip_bfloat16* __restrict__ Cb)
{
  const int l = threadIdx.x & 63, w = threadIdx.x >> 6;
  const long row = (long)blockIdx.x * 4 + w;
  const float* lp = L + row * 1024;
  float v[16];
#pragma unroll
  for (int j = 0; j < 16; ++j) v[j] = lp[j * 64 + l];
  // D: softmax across the 64 lanes for each j (= over p within expert)
#pragma unroll
  for (int j = 0; j < 16; ++j) {
    float m = v[j];
#pragma unroll
    for (int s = 32; s; s >>= 1) m = fmaxf(m, __shfl_xor(m, s));
    const float e = __expf(v[j] - m);
    float sum = e;
#pragma unroll
    for (int s = 32; s; s >>= 1) sum += __shfl_xor(sum, s);
    Db[row * 1024 + j * 64 + l] = __float2bfloat16(e / sum);
  }
  // C: softmax across j (= over experts n) per lane
  float m = v[0];
#pragma unroll
  for (int j = 1; j < 16; ++j) m = fmaxf(m, v[j]);
  float e[16], s = 0.f;
#pragma unroll
  for (int j = 0; j < 16; ++j) { e[j] = __expf(v[j] - m); s += e[j]; }
  const float inv = 1.f / s;
#pragma unroll
  for (int j = 0; j < 16; ++j) Cb[row * 1024 + j * 64 + l] = __float2bfloat16(e[j] * inv);
}

// ---------------- clip + layernorm + tanh -> bf16 ----------------
__global__ __launch_bounds__(256)
void ln_tanh_kernel(const float* __restrict__ X, __hip_bfloat16* __restrict__ Xt)
{
  __shared__ float red[2][4];
  const int t = threadIdx.x;
  const long row = blockIdx.x;
  float4 v = ((const float4*)(X + row * 1024))[t];
  v.x = fminf(fmaxf(v.x, -33000.f), 65000.f);
  v.y = fminf(fmaxf(v.y, -33000.f), 65000.f);
  v.z = fminf(fmaxf(v.z, -33000.f), 65000.f);
  v.w = fminf(fmaxf(v.w, -33000.f), 65000.f);
  float s = v.x + v.y + v.z + v.w;
  float q = v.x * v.x + v.y * v.y + v.z * v.z + v.w * v.w;
#pragma unroll
  for (int m = 32; m; m >>= 1) { s += __shfl_xor(s, m); q += __shfl_xor(q, m); }
  if ((t & 63) == 0) { red[0][t >> 6] = s; red[1][t >> 6] = q; }
  __syncthreads();
  s = red[0][0] + red[0][1] + red[0][2] + red[0][3];
  q = red[1][0] + red[1][1] + red[1][2] + red[1][3];
  const float mu = s * (1.f / 1024.f);
  const float rs = rsqrtf(q * (1.f / 1024.f) - mu * mu + 1e-5f);
  alignas(8) __hip_bfloat16 h[4];
  h[0] = __float2bfloat16(tanhf((v.x - mu) * rs));
  h[1] = __float2bfloat16(tanhf((v.y - mu) * rs));
  h[2] = __float2bfloat16(tanhf((v.z - mu) * rs));
  h[3] = __float2bfloat16(tanhf((v.w - mu) * rs));
  *(uint2*)(Xt + row * 1024 + t * 4) = *(const uint2*)h;
}

// ---------------- generic 128x128 MFMA GEMM: C = A(M,K) * Bt(N,K)^T ----------------
// BIAS_MODE: 0 none, 1 per-col (bias[gcol]), 2 per-row (bias[grow])
template<int BIAS_MODE, bool SPLITK, bool OUT_BF16, bool NMASK>
__global__ __launch_bounds__(256)
void gemm_bt(const __hip_bfloat16* __restrict__ A, const __hip_bfloat16* __restrict__ Bt,
             void* __restrict__ Cp, const float* __restrict__ bias,
             int M, int N, int K, int lda, int ldb, int ldc,
             long sAz, long sBz, long sCz, long sBiasz, int ntn)
{
  __shared__ __hip_bfloat16 As[128 * 32];
  __shared__ __hip_bfloat16 Bs[128 * 32];
  const int t = threadIdx.x, l = t & 63, w = t >> 6;
  // bijective XCD swizzle (grid.x % 8 == 0 for every launch below)
  int bid = blockIdx.x;
  const int nwg = gridDim.x;
  bid = (bid & 7) * (nwg >> 3) + (bid >> 3);
  const int mt = bid / ntn, nt = bid - mt * ntn;
  const long m0 = (long)mt * 128, n0 = (long)nt * 128;
  const int z = blockIdx.z;
  A += (long)z * sAz;
  Bt += (long)z * sBz;
  const long k0 = SPLITK ? (long)z * K : 0;
  const int wr = w >> 1, wc = w & 1;

  f32x4 acc[4][4] = {};

  const int e_l = l * 8;
  for (int kk = 0; kk < K; kk += 32) {
    __syncthreads();
#pragma unroll
    for (int c = 0; c < 2; ++c) {
      const int eb = c * 2048 + w * 512;      // wave-uniform LDS element base
      const int ee = eb + e_l;                // per-lane element (8 bf16 = 16B)
      const int row = ee >> 5, col = ee & 31;
      gload_lds16(A + (m0 + row) * (long)lda + k0 + kk + col, As + eb);
      gload_lds16(Bt + (n0 + row) * (long)ldb + k0 + kk + col, Bs + eb);
    }
    __syncthreads();
    const int fr = l & 15, fk = (l >> 4) * 8;
    bf16x8 af[4], bq[4];
#pragma unroll
    for (int i = 0; i < 4; ++i)
      af[i] = *(const bf16x8*)(As + (wr * 64 + i * 16 + fr) * 32 + fk);
#pragma unroll
    for (int i = 0; i < 4; ++i)
      bq[i] = *(const bf16x8*)(Bs + (wc * 64 + i * 16 + fr) * 32 + fk);
#pragma unroll
    for (int i = 0; i < 4; ++i)
#pragma unroll
      for (int j = 0; j < 4; ++j)
        acc[i][j] = __builtin_amdgcn_mfma_f32_16x16x32_bf16(af[i], bq[j], acc[i][j], 0, 0, 0);
  }

  // epilogue: C/D layout col = lane&15, row = (lane>>4)*4 + reg  [m89/m91]
  const int fr = l & 15, rq = l >> 4;
#pragma unroll
  for (int i = 0; i < 4; ++i) {
    const long grow0 = m0 + wr * 64 + i * 16 + rq * 4;
#pragma unroll
    for (int j = 0; j < 4; ++j) {
      const long gcol = n0 + wc * 64 + j * 16 + fr;
      if (NMASK && gcol >= N) continue;
      float cb = 0.f;
      if (BIAS_MODE == 1) cb = bias[(long)z * sBiasz + gcol];
#pragma unroll
      for (int r = 0; r < 4; ++r) {
        const long grow = grow0 + r;
        float v = acc[i][j][r];
        if (BIAS_MODE == 1) v += cb;
        if (BIAS_MODE == 2) v += bias[(long)z * sBiasz + grow];
        const long off = (long)z * sCz + grow * (long)ldc + gcol;
        if (SPLITK)        atomicAdd((float*)Cp + off, v);
        else if (OUT_BF16) ((__hip_bfloat16*)Cp)[off] = __float2bfloat16(v);
        else               ((float*)Cp)[off] = v;
      }
    }
  }
}

extern "C" void kernel_launch(void* const* d_in, const int* in_sizes, int n_in,
                              void* d_out, int out_size, void* d_ws, size_t ws_size,
                              hipStream_t stream)
{
  (void)in_sizes; (void)n_in; (void)out_size;
  const float* x   = (const float*)d_in[0];
  const float* phw = (const float*)d_in[1];
  const float* phb = (const float*)d_in[2];
  const float* ew  = (const float*)d_in[3];
  const float* eb  = (const float*)d_in[4];
  float* out = (float*)d_out;
  char* ws = (char*)d_ws;

  constexpr long TZ = 36864, DD = 1024, NP = 1024, HH = 4096, NE = 16;

  // arena (with reuse): total ~394 MB
  const size_t o_xbf  = 0;                       // x bf16 (TZ,DD); later D bf16; later ewT (w/ o_xT)
  const size_t o_xT   = o_xbf + TZ * DD * 2;     // x^T bf16 (DD,TZ)
  const size_t o_L    = o_xT + TZ * DD * 2;      // logits f32 (TZ,NP); later Dt bf16 (NP,TZ)
  const size_t o_C    = o_L + TZ * NP * 4;       // C bf16 (TZ,NP)
  const size_t o_phiT = o_C + TZ * NP * 2;       // phi^T bf16 (NP,DD)
  const size_t o_Xtil = o_phiT + DD * NP * 2;    // X_tilde f32 (NP,DD)
  const size_t o_Xt   = o_Xtil + NP * DD * 4;    // X_tilde bf16 post-LN (NP,DD)
  const size_t o_YtT  = o_Xt + NP * DD * 2;      // Y_tilde^T bf16 (HH,NP)
  const size_t need   = o_YtT + HH * NP * 2;
  if (ws_size < need) return;

  __hip_bfloat16* xbf  = (__hip_bfloat16*)(ws + o_xbf);
  __hip_bfloat16* xT   = (__hip_bfloat16*)(ws + o_xT);
  float*          Lg   = (float*)(ws + o_L);
  __hip_bfloat16* Dbf  = (__hip_bfloat16*)(ws + o_xbf);  // alias: x bf16 dead after GEMM1
  __hip_bfloat16* Dt   = (__hip_bfloat16*)(ws + o_L);    // alias: logits dead after softmax
  __hip_bfloat16* Cbf  = (__hip_bfloat16*)(ws + o_C);
  __hip_bfloat16* phiT = (__hip_bfloat16*)(ws + o_phiT);
  float*          Xtl  = (float*)(ws + o_Xtil);
  __hip_bfloat16* Xt   = (__hip_bfloat16*)(ws + o_Xt);
  __hip_bfloat16* YtT  = (__hip_bfloat16*)(ws + o_YtT);
  __hip_bfloat16* ewT  = (__hip_bfloat16*)(ws + o_xbf);  // alias: x/xT dead after GEMM2

  const dim3 B(256);

  // 1. x -> bf16 straight + transposed
  transpose_cast<float, true><<<dim3(TZ / 64, DD / 64, 1), B, 0, stream>>>(
      x, xT, xbf, (int)TZ, (int)DD, 0, 0);
  // 2. phi_w (DD,NP) -> phiT (NP,DD)
  transpose_cast<float, false><<<dim3(DD / 64, NP / 64, 1), B, 0, stream>>>(
      phw, phiT, nullptr, (int)DD, (int)NP, 0, 0);
  // 3. logits = x * phi + b
  gemm_bt<1, false, false, false><<<dim3((TZ / 128) * (NP / 128)), B, 0, stream>>>(
      xbf, phiT, Lg, phb, (int)TZ, (int)NP, (int)DD, (int)DD, (int)DD, (int)NP,
      0, 0, 0, 0, (int)(NP / 128));
  // 4. dual softmax
  softmax_kernel<<<dim3(TZ / 4), B, 0, stream>>>(Lg, Dbf, Cbf);
  // 5. D (TZ,NP) -> Dt (NP,TZ)
  transpose_cast<__hip_bfloat16, false><<<dim3(TZ / 64, NP / 64, 1), B, 0, stream>>>(
      Dbf, Dt, nullptr, (int)TZ, (int)NP, 0, 0);
  // 6. zero X_tilde accumulator
  hipMemsetAsync(Xtl, 0, NP * DD * 4, stream);
  // 7. X_tilde = Dt * xT^T, split-K=16 with fp32 atomics
  gemm_bt<0, true, false, false><<<dim3((NP / 128) * (DD / 128), 1, 16), B, 0, stream>>>(
      Dt, xT, Xtl, nullptr, (int)NP, (int)DD, (int)(TZ / 16), (int)TZ, (int)TZ, (int)DD,
      0, 0, 0, 0, (int)(DD / 128));
  // 8. clip + LN + tanh
  ln_tanh_kernel<<<dim3(NP), B, 0, stream>>>(Xtl, Xt);
  // 9. expert_w (NE,DD,HH) -> ewT (NE,HH,DD)
  transpose_cast<float, false><<<dim3(DD / 64, HH / 64, NE), B, 0, stream>>>(
      ew, ewT, nullptr, (int)DD, (int)HH, DD * HH, HH * DD);
  // 10. Y_tilde^T[h, z*64+p] = ewT[z] * Xt[z]^T + eb[z]  (M=HH, N=64, per-row bias)
  gemm_bt<2, false, true, true><<<dim3(HH / 128, 1, NE), B, 0, stream>>>(
      ewT, Xt, YtT, eb, (int)HH, 64, (int)DD, (int)DD, (int)DD, (int)NP,
      HH * DD, 64 * DD, 64, HH, 1);
  // 11. Y = C * YtT^T
  gemm_bt<0, false, false, false><<<dim3((TZ / 128) * (HH / 128)), B, 0, stream>>>(
      Cbf, YtT, out, nullptr, (int)TZ, (int)HH, (int)NP, (int)NP, (int)NP, (int)HH,
      0, 0, 0, 0, (int)(HH / 128));
}